// Round 9
// baseline (104.774 us; speedup 1.0000x reference)
//
#include <hip/hip_runtime.h>

// InversePreEmphasis: h_t = tanh(x_t + 0.97*h_{t-1}) along T, per row.
// Chunked-parallel with warm-up (per-step contraction 0.97*(1-h^2)).
// R9: abandon intra-thread software pipelining (R4-R8: compiler sinks
// prefetch loads no matter what — asm, sched_barrier, waves_per_eu all
// failed to hold buffers live). Instead: S=32, W=32 -> 1M threads,
// ~32 regs, 8 waves/EU. Load-sinking becomes harmless: TLP (30+ resident
// waves/SIMD-group) hides the ~900cy stalls that ILP couldn't.

constexpr int Bn = 256;
constexpr int T  = 131072;
constexpr int S  = 32;         // outputs per thread (8 float4)
constexpr int C  = T / S;      // 4096 chunks per row
constexpr int W  = 32;         // warm-up steps (8 float4)

// tanh(x + 0.97h) = 1 - 2*rcp(exp2(g*x + 0.97*g*h) + 1),  g = 2*log2(e)
// state r: h = 1-2r;  t = fma(N2CG, r, fma(GLN, x, CGLN))
constexpr float GLN  = 2.885390081777927f;          // 2*log2(e)
constexpr float CGLN = 0.97f * 2.885390081777927f;
constexpr float N2CG = -2.0f * 0.97f * 2.885390081777927f;

__device__ __forceinline__ float step1(float& r, float xin) {
    float t = fmaf(N2CG, r, fmaf(GLN, xin, CGLN));   // inner fmaf off-chain
    float e = __builtin_amdgcn_exp2f(t);
    r = __builtin_amdgcn_rcpf(e + 1.0f);
    return fmaf(-2.0f, r, 1.0f);
}

__device__ __forceinline__ float4 step4(float& r, float4 v) {
    float4 o;
    o.x = step1(r, v.x);
    o.y = step1(r, v.y);
    o.z = step1(r, v.z);
    o.w = step1(r, v.w);
    return o;
}

__global__ __launch_bounds__(256) void ipe_scan_kernel(const float* __restrict__ x,
                                                       float* __restrict__ y) {
    const int tid = blockIdx.x * blockDim.x + threadIdx.x;
    const int b = tid >> 12;           // tid / C, C=4096
    const int c = tid & (C - 1);       // tid % C
    const float* xr = x + ((size_t)b << 17);
    const int start = c * S;

    // c==0: dummy warm-up over x[0..W) (valid memory), state reset below.
    const float4* pw4 = reinterpret_cast<const float4*>(xr + (start >= W ? start - W : 0));
    const float4* pb4 = reinterpret_cast<const float4*>(xr + start);
    float4*       po4 = reinterpret_cast<float4*>(y + ((size_t)b << 17) + start);

    // Issue all loads up front in program order; if the compiler sinks the
    // body loads, TLP covers the stall.
    float4 w0 = pw4[0], w1 = pw4[1], w2 = pw4[2], w3 = pw4[3];
    float4 w4 = pw4[4], w5 = pw4[5], w6 = pw4[6], w7 = pw4[7];
    float4 a0 = pb4[0], a1 = pb4[1], a2 = pb4[2], a3 = pb4[3];
    float4 a4 = pb4[4], a5 = pb4[5], a6 = pb4[6], a7 = pb4[7];

    float r = 0.5f;         // h = 1 - 2r = 0

    // ---- warm-up chain (outputs dead) ----
    (void)step4(r, w0); (void)step4(r, w1); (void)step4(r, w2); (void)step4(r, w3);
    (void)step4(r, w4); (void)step4(r, w5); (void)step4(r, w6); (void)step4(r, w7);

    if (c == 0) r = 0.5f;   // exact h0 = 0 for the first chunk

    // ---- body: chain + store ----
    po4[0] = step4(r, a0); po4[1] = step4(r, a1);
    po4[2] = step4(r, a2); po4[3] = step4(r, a3);
    po4[4] = step4(r, a4); po4[5] = step4(r, a5);
    po4[6] = step4(r, a6); po4[7] = step4(r, a7);
}

extern "C" void kernel_launch(void* const* d_in, const int* in_sizes, int n_in,
                              void* d_out, int out_size, void* d_ws, size_t ws_size,
                              hipStream_t stream) {
    const float* x = (const float*)d_in[0];
    float*       y = (float*)d_out;
    const int total_threads = Bn * (T / S);   // 1048576
    const int block = 256;
    const int grid = total_threads / block;    // 4096
    ipe_scan_kernel<<<grid, block, 0, stream>>>(x, y);
}

// Round 10
// 64.401 us; speedup vs baseline: 1.6269x; 1.6269x over previous
//
#include <hip/hip_runtime.h>

// InversePreEmphasis: h_t = tanh(x_t + 0.97*h_{t-1}) along T, per row.
// Chunked-parallel with warm-up (per-step contraction 0.97*(1-h^2)).
// R10: warm-up data via __shfl_up from the neighbor lane instead of global
// re-reads. Thread c's warm-up window [start-32,start) IS thread c-1's body,
// and with S=W=32 they're adjacent lanes of the same wave. Only lane 0 loads
// warm-up from global (masked, 1/64 traffic). Structurally sink-proof: the
// shuffles consume the body loads, and the warm-up chain precedes the body
// chain, so loads cannot be sunk past one round trip.

constexpr int Bn = 256;
constexpr int T  = 131072;
constexpr int S  = 32;         // outputs per thread (8 float4)
constexpr int C  = T / S;      // 4096 chunks per row
constexpr int W  = 32;         // warm-up steps == S

// tanh(x + 0.97h) = 1 - 2*rcp(exp2(g*x + 0.97*g*h) + 1),  g = 2*log2(e)
// state r: h = 1-2r;  t = fma(N2CG, r, fma(GLN, x, CGLN))
constexpr float GLN  = 2.885390081777927f;          // 2*log2(e)
constexpr float CGLN = 0.97f * 2.885390081777927f;
constexpr float N2CG = -2.0f * 0.97f * 2.885390081777927f;

__device__ __forceinline__ float step1(float& r, float xin) {
    float t = fmaf(N2CG, r, fmaf(GLN, xin, CGLN));   // inner fmaf off-chain
    float e = __builtin_amdgcn_exp2f(t);
    r = __builtin_amdgcn_rcpf(e + 1.0f);
    return fmaf(-2.0f, r, 1.0f);
}

__device__ __forceinline__ float4 step4(float& r, float4 v) {
    float4 o;
    o.x = step1(r, v.x);
    o.y = step1(r, v.y);
    o.z = step1(r, v.z);
    o.w = step1(r, v.w);
    return o;
}

__device__ __forceinline__ float4 shup1(float4 v) {
    float4 t;
    t.x = __shfl_up(v.x, 1, 64);
    t.y = __shfl_up(v.y, 1, 64);
    t.z = __shfl_up(v.z, 1, 64);
    t.w = __shfl_up(v.w, 1, 64);
    return t;
}

__global__ __launch_bounds__(256) void ipe_scan_kernel(const float* __restrict__ x,
                                                       float* __restrict__ y) {
    const int tid  = blockIdx.x * blockDim.x + threadIdx.x;
    const int b    = tid >> 12;           // / C (C=4096)
    const int c    = tid & (C - 1);       // % C
    const int lane = threadIdx.x & 63;    // == c & 63 (4096 % 64 == 0)
    const float* xr = x + ((size_t)b << 17);
    const int start = c * S;

    const float4* pb4 = reinterpret_cast<const float4*>(xr + start);
    float4*       po4 = reinterpret_cast<float4*>(y + ((size_t)b << 17) + start);

    // ---- body loads: the only full-wave global reads ----
    float4 a0 = pb4[0], a1 = pb4[1], a2 = pb4[2], a3 = pb4[3];
    float4 a4 = pb4[4], a5 = pb4[5], a6 = pb4[6], a7 = pb4[7];

    // ---- warm-up data: previous lane's body; lane 0 loads from global ----
    float4 w0, w1, w2, w3, w4, w5, w6, w7;
    if (lane == 0) {
        // c==0 uses x[0..W) as dummy (state reset below); else exact window.
        const float4* pw4 =
            reinterpret_cast<const float4*>(xr + (start >= W ? start - W : 0));
        w0 = pw4[0]; w1 = pw4[1]; w2 = pw4[2]; w3 = pw4[3];
        w4 = pw4[4]; w5 = pw4[5]; w6 = pw4[6]; w7 = pw4[7];
    }
    float4 t0 = shup1(a0), t1 = shup1(a1), t2 = shup1(a2), t3 = shup1(a3);
    float4 t4 = shup1(a4), t5 = shup1(a5), t6 = shup1(a6), t7 = shup1(a7);
    if (lane != 0) {
        w0 = t0; w1 = t1; w2 = t2; w3 = t3;
        w4 = t4; w5 = t5; w6 = t6; w7 = t7;
    }

    float r = 0.5f;         // h = 1 - 2r = 0

    // ---- warm-up chain (outputs dead) ----
    (void)step4(r, w0); (void)step4(r, w1); (void)step4(r, w2); (void)step4(r, w3);
    (void)step4(r, w4); (void)step4(r, w5); (void)step4(r, w6); (void)step4(r, w7);

    if (c == 0) r = 0.5f;   // exact h0 = 0 for the first chunk

    // ---- body: chain + store ----
    po4[0] = step4(r, a0); po4[1] = step4(r, a1);
    po4[2] = step4(r, a2); po4[3] = step4(r, a3);
    po4[4] = step4(r, a4); po4[5] = step4(r, a5);
    po4[6] = step4(r, a6); po4[7] = step4(r, a7);
}

extern "C" void kernel_launch(void* const* d_in, const int* in_sizes, int n_in,
                              void* d_out, int out_size, void* d_ws, size_t ws_size,
                              hipStream_t stream) {
    const float* x = (const float*)d_in[0];
    float*       y = (float*)d_out;
    const int total_threads = Bn * C;          // 1048576
    const int block = 256;
    const int grid = total_threads / block;    // 4096
    ipe_scan_kernel<<<grid, block, 0, stream>>>(x, y);
}

// Round 11
// 61.988 us; speedup vs baseline: 1.6902x; 1.0389x over previous
//
#include <hip/hip_runtime.h>

// InversePreEmphasis: h_t = tanh(x_t + 0.97*h_{t-1}) along T, per row.
// Chunked-parallel with warm-up (per-step contraction 0.97*(1-h^2)).
// R11: R10 structure, W=32->24 (per-thread steps 64->56, shuffles 32->24;
// truncation-failure expectation ~3e-4 chunks at W=24), and lane-0's
// warm-up global loads issued FIRST (whole wave stalls on lane 0 in SIMT,
// so their latency must overlap the body loads, not follow them).

constexpr int Bn = 256;
constexpr int T  = 131072;
constexpr int S  = 32;         // outputs per thread (8 float4)
constexpr int C  = T / S;      // 4096 chunks per row
constexpr int W  = 24;         // warm-up steps (6 float4)

// tanh(x + 0.97h) = 1 - 2*rcp(exp2(g*x + 0.97*g*h) + 1),  g = 2*log2(e)
// state r: h = 1-2r;  t = fma(N2CG, r, fma(GLN, x, CGLN))
constexpr float GLN  = 2.885390081777927f;          // 2*log2(e)
constexpr float CGLN = 0.97f * 2.885390081777927f;
constexpr float N2CG = -2.0f * 0.97f * 2.885390081777927f;

__device__ __forceinline__ float step1(float& r, float xin) {
    float t = fmaf(N2CG, r, fmaf(GLN, xin, CGLN));   // inner fmaf off-chain
    float e = __builtin_amdgcn_exp2f(t);
    r = __builtin_amdgcn_rcpf(e + 1.0f);
    return fmaf(-2.0f, r, 1.0f);
}

__device__ __forceinline__ float4 step4(float& r, float4 v) {
    float4 o;
    o.x = step1(r, v.x);
    o.y = step1(r, v.y);
    o.z = step1(r, v.z);
    o.w = step1(r, v.w);
    return o;
}

__device__ __forceinline__ float4 shup1(float4 v) {
    float4 t;
    t.x = __shfl_up(v.x, 1, 64);
    t.y = __shfl_up(v.y, 1, 64);
    t.z = __shfl_up(v.z, 1, 64);
    t.w = __shfl_up(v.w, 1, 64);
    return t;
}

__global__ __launch_bounds__(256) void ipe_scan_kernel(const float* __restrict__ x,
                                                       float* __restrict__ y) {
    const int tid  = blockIdx.x * blockDim.x + threadIdx.x;
    const int b    = tid >> 12;           // / C (C=4096)
    const int c    = tid & (C - 1);       // % C
    const int lane = threadIdx.x & 63;    // == c & 63 (4096 % 64 == 0)
    const float* xr = x + ((size_t)b << 17);
    const int start = c * S;

    const float4* pb4 = reinterpret_cast<const float4*>(xr + start);
    float4*       po4 = reinterpret_cast<float4*>(y + ((size_t)b << 17) + start);

    // ---- lane 0's warm-up loads issued FIRST (whole wave stalls on lane 0) ----
    float4 w0, w1, w2, w3, w4, w5;
    if (lane == 0) {
        // c==0 uses x[0..W) as dummy (state reset below); else exact window.
        const float4* pw4 =
            reinterpret_cast<const float4*>(xr + (start >= W ? start - W : 0));
        w0 = pw4[0]; w1 = pw4[1]; w2 = pw4[2];
        w3 = pw4[3]; w4 = pw4[4]; w5 = pw4[5];
    }

    // ---- body loads: the only full-wave global reads ----
    float4 a0 = pb4[0], a1 = pb4[1], a2 = pb4[2], a3 = pb4[3];
    float4 a4 = pb4[4], a5 = pb4[5], a6 = pb4[6], a7 = pb4[7];

    // ---- other lanes' warm-up = last W elems of previous lane's body ----
    float4 t0 = shup1(a2), t1 = shup1(a3), t2 = shup1(a4);
    float4 t3 = shup1(a5), t4 = shup1(a6), t5 = shup1(a7);
    if (lane != 0) {
        w0 = t0; w1 = t1; w2 = t2;
        w3 = t3; w4 = t4; w5 = t5;
    }

    float r = 0.5f;         // h = 1 - 2r = 0

    // ---- warm-up chain (outputs dead) ----
    (void)step4(r, w0); (void)step4(r, w1); (void)step4(r, w2);
    (void)step4(r, w3); (void)step4(r, w4); (void)step4(r, w5);

    if (c == 0) r = 0.5f;   // exact h0 = 0 for the first chunk

    // ---- body: chain + store ----
    po4[0] = step4(r, a0); po4[1] = step4(r, a1);
    po4[2] = step4(r, a2); po4[3] = step4(r, a3);
    po4[4] = step4(r, a4); po4[5] = step4(r, a5);
    po4[6] = step4(r, a6); po4[7] = step4(r, a7);
}

extern "C" void kernel_launch(void* const* d_in, const int* in_sizes, int n_in,
                              void* d_out, int out_size, void* d_ws, size_t ws_size,
                              hipStream_t stream) {
    const float* x = (const float*)d_in[0];
    float*       y = (float*)d_out;
    const int total_threads = Bn * C;          // 1048576
    const int block = 256;
    const int grid = total_threads / block;    // 4096
    ipe_scan_kernel<<<grid, block, 0, stream>>>(x, y);
}

// Round 12
// 45.175 us; speedup vs baseline: 2.3193x; 1.3722x over previous
//
#include <hip/hip_runtime.h>

// InversePreEmphasis: h_t = tanh(x_t + 0.97*h_{t-1}) along T, per row.
// Chunked-parallel with shuffle warm-up (R10/R11 structure).
// R12: kill VMEM transaction amplification. Per-lane-contiguous chunks made
// every global instr a 64-line scatter (~1030 line-transactions/wave).
// Now: coalesced 1KB-per-instr global loads/stores + per-wave LDS
// redistribution (XOR-swizzled rows, bank-balanced). No s_barrier needed:
// all LDS hazards are within-wave, ordered by compiler lgkmcnt waits.

constexpr int Bn = 256;
constexpr int T  = 131072;
constexpr int S  = 32;         // outputs per thread (8 float4)
constexpr int C  = T / S;      // 4096 chunks per row
constexpr int W  = 24;         // warm-up steps (6 float4) — validated in R11

// tanh(x + 0.97h) = 1 - 2*rcp(exp2(g*x + 0.97*g*h) + 1),  g = 2*log2(e)
constexpr float GLN  = 2.885390081777927f;          // 2*log2(e)
constexpr float CGLN = 0.97f * 2.885390081777927f;
constexpr float N2CG = -2.0f * 0.97f * 2.885390081777927f;

__device__ __forceinline__ float step1(float& r, float xin) {
    float t = fmaf(N2CG, r, fmaf(GLN, xin, CGLN));
    float e = __builtin_amdgcn_exp2f(t);
    r = __builtin_amdgcn_rcpf(e + 1.0f);
    return fmaf(-2.0f, r, 1.0f);
}

__device__ __forceinline__ float4 step4(float& r, float4 v) {
    float4 o;
    o.x = step1(r, v.x);
    o.y = step1(r, v.y);
    o.z = step1(r, v.z);
    o.w = step1(r, v.w);
    return o;
}

__device__ __forceinline__ float4 shup1(float4 v) {
    float4 t;
    t.x = __shfl_up(v.x, 1, 64);
    t.y = __shfl_up(v.y, 1, 64);
    t.z = __shfl_up(v.z, 1, 64);
    t.w = __shfl_up(v.w, 1, 64);
    return t;
}

// LDS slot for (row, pos): row = chunk-within-wave (0..63, 128B each),
// pos = float4 within chunk (0..7). XOR swizzle balances banks.
__device__ __forceinline__ int slot(int row, int pos) {
    return row * 8 + (pos ^ (row & 7));
}

__global__ __launch_bounds__(256) void ipe_scan_kernel(const float* __restrict__ x,
                                                       float* __restrict__ y) {
    const int tid  = blockIdx.x * blockDim.x + threadIdx.x;
    const int b    = tid >> 12;           // / C (C=4096)
    const int c    = tid & (C - 1);       // % C
    const int lane = threadIdx.x & 63;
    const int wv   = threadIdx.x >> 6;    // wave id within block (0..3)
    const float* xr = x + ((size_t)b << 17);
    float*       yr = y + ((size_t)b << 17);
    const int start = c * S;

    __shared__ float4 lds[4 * 512];       // 8KB slice per wave
    float4* sl = lds + wv * 512;

    // This wave covers 64 consecutive chunks = 512 float4 = 8KB.
    const int base = (c & ~63) * S;       // float offset of wave's region
    const float4* gb = reinterpret_cast<const float4*>(xr + base);
    float4*       ob = reinterpret_cast<float4*>(yr + base);

    // ---- lane 0's warm-up loads issued first (wave stalls on lane 0) ----
    float4 w0, w1, w2, w3, w4, w5;
    if (lane == 0) {
        const float4* pw =
            reinterpret_cast<const float4*>(xr + (start >= W ? start - W : 0));
        w0 = pw[0]; w1 = pw[1]; w2 = pw[2];
        w3 = pw[3]; w4 = pw[4]; w5 = pw[5];
    }

    // ---- coalesced loads (1KB/instr) -> LDS chunk-rows (swizzled) ----
#pragma unroll
    for (int k = 0; k < 8; ++k) {
        const int f = k * 64 + lane;          // float4 index in wave region
        float4 g = gb[f];                     // lanes contiguous: coalesced
        sl[slot(f >> 3, f & 7)] = g;
    }

    // ---- each lane reads its own contiguous chunk from LDS ----
    float4 a0 = sl[slot(lane, 0)], a1 = sl[slot(lane, 1)];
    float4 a2 = sl[slot(lane, 2)], a3 = sl[slot(lane, 3)];
    float4 a4 = sl[slot(lane, 4)], a5 = sl[slot(lane, 5)];
    float4 a6 = sl[slot(lane, 6)], a7 = sl[slot(lane, 7)];

    // ---- warm-up = last W elems of previous lane's chunk, via shuffle ----
    float4 t0 = shup1(a2), t1 = shup1(a3), t2 = shup1(a4);
    float4 t3 = shup1(a5), t4 = shup1(a6), t5 = shup1(a7);
    if (lane != 0) {
        w0 = t0; w1 = t1; w2 = t2;
        w3 = t3; w4 = t4; w5 = t5;
    }

    float r = 0.5f;         // h = 1 - 2r = 0

    // ---- warm-up chain (outputs dead) ----
    (void)step4(r, w0); (void)step4(r, w1); (void)step4(r, w2);
    (void)step4(r, w3); (void)step4(r, w4); (void)step4(r, w5);

    if (c == 0) r = 0.5f;   // exact h0 = 0 for the first chunk

    // ---- body chain; stage results into own LDS row (no cross-lane hazard:
    //      each lane reads only its row above and writes only its row here) ----
    sl[slot(lane, 0)] = step4(r, a0);
    sl[slot(lane, 1)] = step4(r, a1);
    sl[slot(lane, 2)] = step4(r, a2);
    sl[slot(lane, 3)] = step4(r, a3);
    sl[slot(lane, 4)] = step4(r, a4);
    sl[slot(lane, 5)] = step4(r, a5);
    sl[slot(lane, 6)] = step4(r, a6);
    sl[slot(lane, 7)] = step4(r, a7);

    // ---- coalesced stores (1KB/instr) from LDS round-major reads ----
#pragma unroll
    for (int k = 0; k < 8; ++k) {
        const int f = k * 64 + lane;
        ob[f] = sl[slot(f >> 3, f & 7)];
    }
}

extern "C" void kernel_launch(void* const* d_in, const int* in_sizes, int n_in,
                              void* d_out, int out_size, void* d_ws, size_t ws_size,
                              hipStream_t stream) {
    const float* x = (const float*)d_in[0];
    float*       y = (float*)d_out;
    const int total_threads = Bn * C;          // 1048576
    const int block = 256;
    const int grid = total_threads / block;    // 4096
    ipe_scan_kernel<<<grid, block, 0, stream>>>(x, y);
}

// Round 13
// 44.678 us; speedup vs baseline: 2.3451x; 1.0111x over previous
//
#include <hip/hip_runtime.h>

// InversePreEmphasis: h_t = tanh(x_t + 0.97*h_{t-1}) along T, per row.
// Chunked-parallel with shuffle warm-up + per-wave LDS coalescing (R12).
// R13: S=32->16 to double occupancy (LDS 16KB/block -> 10 blocks/CU;
// VGPR small -> 8 waves/SIMD). Warm-up W=24 spans 2 predecessor chunks:
// shfl_up 1 and 2; lanes 0-1 fall back to global; chunks 0,1 exact via
// staged state resets.

constexpr int Bn = 256;
constexpr int T  = 131072;
constexpr int S  = 16;         // outputs per thread (4 float4)
constexpr int C  = T / S;      // 8192 chunks per row
constexpr int W  = 24;         // warm-up steps (6 float4)

// tanh(x + 0.97h) = 1 - 2*rcp(exp2(g*x + 0.97*g*h) + 1),  g = 2*log2(e)
constexpr float GLN  = 2.885390081777927f;          // 2*log2(e)
constexpr float CGLN = 0.97f * 2.885390081777927f;
constexpr float N2CG = -2.0f * 0.97f * 2.885390081777927f;

__device__ __forceinline__ float step1(float& r, float xin) {
    float t = fmaf(N2CG, r, fmaf(GLN, xin, CGLN));
    float e = __builtin_amdgcn_exp2f(t);
    r = __builtin_amdgcn_rcpf(e + 1.0f);
    return fmaf(-2.0f, r, 1.0f);
}

__device__ __forceinline__ float4 step4(float& r, float4 v) {
    float4 o;
    o.x = step1(r, v.x);
    o.y = step1(r, v.y);
    o.z = step1(r, v.z);
    o.w = step1(r, v.w);
    return o;
}

__device__ __forceinline__ float4 shup(float4 v, int d) {
    float4 t;
    t.x = __shfl_up(v.x, d, 64);
    t.y = __shfl_up(v.y, d, 64);
    t.z = __shfl_up(v.z, d, 64);
    t.w = __shfl_up(v.w, d, 64);
    return t;
}

// LDS slot for (row=chunk 0..63, pos=float4 0..3). XOR swizzle balances banks.
__device__ __forceinline__ int slot(int row, int pos) {
    return (row << 2) + (pos ^ (row & 3));
}

__global__ __launch_bounds__(256) void ipe_scan_kernel(const float* __restrict__ x,
                                                       float* __restrict__ y) {
    const int tid  = blockIdx.x * blockDim.x + threadIdx.x;
    const int b    = tid >> 13;           // / C (C=8192)
    const int c    = tid & (C - 1);       // % C
    const int lane = threadIdx.x & 63;
    const int wv   = threadIdx.x >> 6;
    const float* xr = x + ((size_t)b << 17);
    float*       yr = y + ((size_t)b << 17);
    const int start = c * S;

    __shared__ float4 lds[4 * 256];       // 4KB slice per wave
    float4* sl = lds + wv * 256;

    // Wave region: 64 chunks = 1024 floats = 256 float4.
    const int base = (c & ~63) * S;
    const float4* gb = reinterpret_cast<const float4*>(xr + base);
    float4*       ob = reinterpret_cast<float4*>(yr + base);

    // ---- lanes 0-1 warm-up fallback loads issued first ----
    float4 w0, w1, w2, w3, w4, w5;
    if (lane == 0) {
        // c==0: dummy window [0,24) (r reset below); else exact window.
        const float4* pw =
            reinterpret_cast<const float4*>(xr + (start >= W ? start - W : 0));
        w0 = pw[0]; w1 = pw[1]; w2 = pw[2];
        w3 = pw[3]; w4 = pw[4]; w5 = pw[5];
    }
    if (lane == 1) {
        // needs [start-24, start-16); c==1 -> dummy [0,8) (r reset below).
        const float4* pv =
            reinterpret_cast<const float4*>(xr + (start >= W ? start - W : 0));
        w0 = pv[0]; w1 = pv[1];
    }

    // ---- coalesced loads (1KB/instr) -> LDS rows (swizzled) ----
#pragma unroll
    for (int k = 0; k < 4; ++k) {
        const int f = k * 64 + lane;
        float4 g = gb[f];
        sl[slot(f >> 2, f & 3)] = g;
    }

    // ---- each lane reads its own chunk (4 float4) from LDS ----
    float4 a0 = sl[slot(lane, 0)], a1 = sl[slot(lane, 1)];
    float4 a2 = sl[slot(lane, 2)], a3 = sl[slot(lane, 3)];

    // ---- warm-up: last 8 of lane-2's chunk + all 16 of lane-1's chunk ----
    float4 t0 = shup(a2, 2), t1 = shup(a3, 2);
    float4 t2 = shup(a0, 1), t3 = shup(a1, 1);
    float4 t4 = shup(a2, 1), t5 = shup(a3, 1);
    if (lane >= 2) { w0 = t0; w1 = t1; }
    if (lane >= 1) { w2 = t2; w3 = t3; w4 = t4; w5 = t5; }

    float r = 0.5f;          // h = 1 - 2r = 0

    // ---- warm-up chain (outputs dead), with exact resets for c=0,1 ----
    (void)step4(r, w0); (void)step4(r, w1);
    if (start == S) r = 0.5f;     // c==1: exact prefix = chunk 0 only
    (void)step4(r, w2); (void)step4(r, w3);
    (void)step4(r, w4); (void)step4(r, w5);
    if (start == 0) r = 0.5f;     // c==0: exact h0 = 0

    // ---- body chain; stage results into own LDS row ----
    sl[slot(lane, 0)] = step4(r, a0);
    sl[slot(lane, 1)] = step4(r, a1);
    sl[slot(lane, 2)] = step4(r, a2);
    sl[slot(lane, 3)] = step4(r, a3);

    // ---- coalesced stores (1KB/instr) ----
#pragma unroll
    for (int k = 0; k < 4; ++k) {
        const int f = k * 64 + lane;
        ob[f] = sl[slot(f >> 2, f & 3)];
    }
}

extern "C" void kernel_launch(void* const* d_in, const int* in_sizes, int n_in,
                              void* d_out, int out_size, void* d_ws, size_t ws_size,
                              hipStream_t stream) {
    const float* x = (const float*)d_in[0];
    float*       y = (float*)d_out;
    const int total_threads = Bn * C;          // 2097152
    const int block = 256;
    const int grid = total_threads / block;    // 8192
    ipe_scan_kernel<<<grid, block, 0, stream>>>(x, y);
}

// Round 14
// 44.419 us; speedup vs baseline: 2.3588x; 1.0058x over previous
//
#include <hip/hip_runtime.h>

// InversePreEmphasis: h_t = tanh(x_t + 0.97*h_{t-1}) along T, per row.
// Chunked-parallel with shuffle warm-up + per-wave LDS coalescing (R12/R13).
// R14: non-temporal output stores. Input(134MB)+output(134MB) thrash the
// 256MB Infinity Cache (FETCH showed only half the input L3-served). The
// output is write-once -> nt stores keep it from evicting the input, so
// replay-steady-state reads come from L3 and HBM sees ~only the writes.

constexpr int Bn = 256;
constexpr int T  = 131072;
constexpr int S  = 16;         // outputs per thread (4 float4)
constexpr int C  = T / S;      // 8192 chunks per row
constexpr int W  = 24;         // warm-up steps (6 float4)

// tanh(x + 0.97h) = 1 - 2*rcp(exp2(g*x + 0.97*g*h) + 1),  g = 2*log2(e)
constexpr float GLN  = 2.885390081777927f;          // 2*log2(e)
constexpr float CGLN = 0.97f * 2.885390081777927f;
constexpr float N2CG = -2.0f * 0.97f * 2.885390081777927f;

typedef float v4f __attribute__((ext_vector_type(4)));

__device__ __forceinline__ float step1(float& r, float xin) {
    float t = fmaf(N2CG, r, fmaf(GLN, xin, CGLN));
    float e = __builtin_amdgcn_exp2f(t);
    r = __builtin_amdgcn_rcpf(e + 1.0f);
    return fmaf(-2.0f, r, 1.0f);
}

__device__ __forceinline__ float4 step4(float& r, float4 v) {
    float4 o;
    o.x = step1(r, v.x);
    o.y = step1(r, v.y);
    o.z = step1(r, v.z);
    o.w = step1(r, v.w);
    return o;
}

__device__ __forceinline__ float4 shup(float4 v, int d) {
    float4 t;
    t.x = __shfl_up(v.x, d, 64);
    t.y = __shfl_up(v.y, d, 64);
    t.z = __shfl_up(v.z, d, 64);
    t.w = __shfl_up(v.w, d, 64);
    return t;
}

// LDS slot for (row=chunk 0..63, pos=float4 0..3). XOR swizzle balances banks.
__device__ __forceinline__ int slot(int row, int pos) {
    return (row << 2) + (pos ^ (row & 3));
}

__global__ __launch_bounds__(256) void ipe_scan_kernel(const float* __restrict__ x,
                                                       float* __restrict__ y) {
    const int tid  = blockIdx.x * blockDim.x + threadIdx.x;
    const int b    = tid >> 13;           // / C (C=8192)
    const int c    = tid & (C - 1);       // % C
    const int lane = threadIdx.x & 63;
    const int wv   = threadIdx.x >> 6;
    const float* xr = x + ((size_t)b << 17);
    float*       yr = y + ((size_t)b << 17);
    const int start = c * S;

    __shared__ float4 lds[4 * 256];       // 4KB slice per wave
    float4* sl = lds + wv * 256;

    // Wave region: 64 chunks = 1024 floats = 256 float4.
    const int base = (c & ~63) * S;
    const float4* gb = reinterpret_cast<const float4*>(xr + base);
    float4*       ob = reinterpret_cast<float4*>(yr + base);

    // ---- lanes 0-1 warm-up fallback loads issued first ----
    float4 w0, w1, w2, w3, w4, w5;
    if (lane == 0) {
        // c==0: dummy window [0,24) (r reset below); else exact window.
        const float4* pw =
            reinterpret_cast<const float4*>(xr + (start >= W ? start - W : 0));
        w0 = pw[0]; w1 = pw[1]; w2 = pw[2];
        w3 = pw[3]; w4 = pw[4]; w5 = pw[5];
    }
    if (lane == 1) {
        // needs [start-24, start-16); c==1 -> dummy [0,8) (r reset below).
        const float4* pv =
            reinterpret_cast<const float4*>(xr + (start >= W ? start - W : 0));
        w0 = pv[0]; w1 = pv[1];
    }

    // ---- coalesced loads (1KB/instr) -> LDS rows (swizzled) ----
#pragma unroll
    for (int k = 0; k < 4; ++k) {
        const int f = k * 64 + lane;
        float4 g = gb[f];
        sl[slot(f >> 2, f & 3)] = g;
    }

    // ---- each lane reads its own chunk (4 float4) from LDS ----
    float4 a0 = sl[slot(lane, 0)], a1 = sl[slot(lane, 1)];
    float4 a2 = sl[slot(lane, 2)], a3 = sl[slot(lane, 3)];

    // ---- warm-up: last 8 of lane-2's chunk + all 16 of lane-1's chunk ----
    float4 t0 = shup(a2, 2), t1 = shup(a3, 2);
    float4 t2 = shup(a0, 1), t3 = shup(a1, 1);
    float4 t4 = shup(a2, 1), t5 = shup(a3, 1);
    if (lane >= 2) { w0 = t0; w1 = t1; }
    if (lane >= 1) { w2 = t2; w3 = t3; w4 = t4; w5 = t5; }

    float r = 0.5f;          // h = 1 - 2r = 0

    // ---- warm-up chain (outputs dead), with exact resets for c=0,1 ----
    (void)step4(r, w0); (void)step4(r, w1);
    if (start == S) r = 0.5f;     // c==1: exact prefix = chunk 0 only
    (void)step4(r, w2); (void)step4(r, w3);
    (void)step4(r, w4); (void)step4(r, w5);
    if (start == 0) r = 0.5f;     // c==0: exact h0 = 0

    // ---- body chain; stage results into own LDS row ----
    sl[slot(lane, 0)] = step4(r, a0);
    sl[slot(lane, 1)] = step4(r, a1);
    sl[slot(lane, 2)] = step4(r, a2);
    sl[slot(lane, 3)] = step4(r, a3);

    // ---- coalesced NON-TEMPORAL stores (1KB/instr, don't pollute L3) ----
#pragma unroll
    for (int k = 0; k < 4; ++k) {
        const int f = k * 64 + lane;
        float4 v = sl[slot(f >> 2, f & 3)];
        v4f vv = {v.x, v.y, v.z, v.w};
        __builtin_nontemporal_store(vv, reinterpret_cast<v4f*>(ob + f));
    }
}

extern "C" void kernel_launch(void* const* d_in, const int* in_sizes, int n_in,
                              void* d_out, int out_size, void* d_ws, size_t ws_size,
                              hipStream_t stream) {
    const float* x = (const float*)d_in[0];
    float*       y = (float*)d_out;
    const int total_threads = Bn * C;          // 2097152
    const int block = 256;
    const int grid = total_threads / block;    // 8192
    ipe_scan_kernel<<<grid, block, 0, stream>>>(x, y);
}